// Round 5
// baseline (449.032 us; speedup 1.0000x reference)
//
#include <hip/hip_runtime.h>
#include <hip/hip_cooperative_groups.h>
#include <stdint.h>
#include <math.h>

#define ROWLEN 84
#define F4PR 21            // float4s per row (84 floats)
#define RPB 256            // rows per tile
#define F4PT (RPB * F4PR)  // 5376 float4s per tile
#define TIECAP 16384u

namespace cg = cooperative_groups;

__device__ __forceinline__ uint32_t map_f(float f) {
    uint32_t u = __float_as_uint(f);
    return (u & 0x80000000u) ? ~u : (u | 0x80000000u);
}
__device__ __forceinline__ float unmap_f(uint32_t u) {
    uint32_t b = (u & 0x80000000u) ? (u & 0x7FFFFFFFu) : ~u;
    return __uint_as_float(b);
}

// Parallel bin find: bin b with suffix_count(b+1..) < target <= suffix_count(b..).
// All 256 threads participate; returns identical (bin, count-strictly-above) to all.
__device__ void find_parallel(const uint32_t* __restrict__ hist, int nbins, uint32_t target,
                              uint32_t* s, uint32_t* sc2, uint32_t* outBin, uint32_t* outAbove) {
    int tid = threadIdx.x;
    int chunks = nbins / 256;
    int base = tid * chunks;
    uint32_t part = 0;
    for (int i = 0; i < chunks; ++i) part += hist[base + i];
    s[tid] = part;
    __syncthreads();
    for (int off = 1; off < 256; off <<= 1) {  // suffix sums
        uint32_t v = (tid + off < 256) ? s[tid + off] : 0u;
        __syncthreads();
        s[tid] += v;
        __syncthreads();
    }
    uint32_t above_next = (tid < 255) ? s[tid + 1] : 0u;
    bool mine = (s[tid] >= target) && (above_next < target);  // exactly one thread
    if (mine) { sc2[0] = (uint32_t)tid; sc2[1] = above_next; }
    __syncthreads();
    uint32_t c = sc2[0], above = sc2[1];
    if (tid == 0) {  // <= chunks serial reads
        uint32_t acc = above;
        int b = (int)c * chunks + chunks - 1;
        for (;; --b) {
            uint32_t hb = hist[b];
            if (acc + hb >= target) break;
            acc += hb;
        }
        sc2[0] = (uint32_t)b;
        sc2[1] = acc;
    }
    __syncthreads();
    *outBin = sc2[0];
    *outAbove = sc2[1];
}

// ======================= cooperative fused path =======================

struct SMem {
    union {
        struct { float pm[F4PT]; uint32_t h[1024]; } p1;
        struct { uint32_t h[2048]; uint32_t s[256]; uint32_t sc2[2]; float wsum[4]; } p2;
    } u;
    int s_tile;
};

__global__ __launch_bounds__(256, 4) void k_fused(const float* __restrict__ pred,
                                                  uint32_t* __restrict__ scores,
                                                  uint32_t* __restrict__ gH1,
                                                  uint32_t* __restrict__ gH2,
                                                  uint32_t* __restrict__ gH3,
                                                  uint32_t* __restrict__ tieCnt,
                                                  uint32_t* __restrict__ ticket,
                                                  uint32_t* __restrict__ tieBuf,
                                                  float* __restrict__ out,
                                                  int n, uint32_t K) {
    cg::grid_group grid = cg::this_grid();
    __shared__ SMem sm;
    int tid = threadIdx.x;
    int gid = blockIdx.x * 256 + tid;
    int gstride = gridDim.x * 256;

    // ---- P0: zero metadata (replaces memsets) ----
    for (int i = gid; i < 1024; i += gstride) gH1[i] = 0;
    for (int i = gid; i < 2048; i += gstride) { gH2[i] = 0; gH3[i] = 0; }
    if (gid == 0) { *tieCnt = 0; *ticket = 0; *out = 0.f; }
    grid.sync();

    // ---- P1: scores + level-1 histogram (top 10 bits), ticket-scheduled LDS tiles ----
    for (int i = tid; i < 1024; i += 256) sm.u.p1.h[i] = 0;
    uint32_t tid21 = (uint32_t)tid % 21u;
    const float4* pf4 = (const float4*)pred;
    size_t total_f4 = (size_t)n * F4PR;
    int ntiles = (n + RPB - 1) / RPB;
    for (;;) {
        __syncthreads();  // pm/s_tile reuse guard (also covers h init on first pass)
        if (tid == 0) sm.s_tile = (int)atomicAdd(ticket, 1u);
        __syncthreads();
        int tile = sm.s_tile;
        if (tile >= ntiles) break;
        size_t gbase = (size_t)tile * F4PT;
        int row0 = tile * RPB;
        if (row0 + RPB <= n) {
#pragma unroll
            for (int it = 0; it < F4PR; ++it) {
                const uint32_t BP = (21u - (4u * (uint32_t)it) % 21u) % 21u;  // box lane
                float4 v = pf4[gbase + it * 256 + tid];
                float m = fmaxf(fmaxf(v.x, v.y), fmaxf(v.z, v.w));
                sm.u.p1.pm[it * 256 + tid] = (tid21 == BP) ? -INFINITY : m;
            }
        } else {
#pragma unroll
            for (int it = 0; it < F4PR; ++it) {
                const uint32_t BP = (21u - (4u * (uint32_t)it) % 21u) % 21u;
                int l = it * 256 + tid;
                size_t g = gbase + l;
                float m = -INFINITY;
                if (g < total_f4 && tid21 != BP) {
                    float4 v = pf4[g];
                    m = fmaxf(fmaxf(v.x, v.y), fmaxf(v.z, v.w));
                }
                sm.u.p1.pm[l] = m;
            }
        }
        __syncthreads();
        int row = row0 + tid;
        if (row < n) {
            const float* q = sm.u.p1.pm + tid * F4PR;
            float m = q[1];
#pragma unroll
            for (int j = 2; j <= 20; ++j) m = fmaxf(m, q[j]);
            uint32_t u = map_f(m);
            scores[row] = u;
            atomicAdd(&sm.u.p1.h[u >> 22], 1u);
        }
    }
    __syncthreads();
    for (int i = tid; i < 1024; i += 256) {
        uint32_t hv = sm.u.p1.h[i];
        if (hv) atomicAdd(&gH1[i], hv);
    }
    grid.sync();

    // ---- P2: find bin1; level-2 histogram (bits [21:11]) ----
    for (int i = tid; i < 2048; i += 256) sm.u.p2.h[i] = 0;
    uint32_t bin1, chi1;
    find_parallel(gH1, 1024, K, sm.u.p2.s, sm.u.p2.sc2, &bin1, &chi1);
    for (int r = gid; r < n; r += gstride) {
        uint32_t u = scores[r];
        if ((u >> 22) == bin1) atomicAdd(&sm.u.p2.h[(u >> 11) & 0x7FFu], 1u);
    }
    __syncthreads();
    for (int i = tid; i < 2048; i += 256) {
        uint32_t hv = sm.u.p2.h[i];
        if (hv) atomicAdd(&gH2[i], hv);
    }
    grid.sync();

    // ---- P3: find bin2; level-3 histogram (bits [10:0]) ----
    for (int i = tid; i < 2048; i += 256) sm.u.p2.h[i] = 0;
    uint32_t bin2, chi2;
    find_parallel(gH2, 2048, K - chi1, sm.u.p2.s, sm.u.p2.sc2, &bin2, &chi2);
    uint32_t pref = (bin1 << 11) | bin2;
    for (int r = gid; r < n; r += gstride) {
        uint32_t u = scores[r];
        if ((u >> 11) == pref) atomicAdd(&sm.u.p2.h[u & 0x7FFu], 1u);
    }
    __syncthreads();
    for (int i = tid; i < 2048; i += 256) {
        uint32_t hv = sm.u.p2.h[i];
        if (hv) atomicAdd(&gH3[i], hv);
    }
    grid.sync();

    // ---- P4: find bin3 -> threshold; selection sum; record ties ----
    uint32_t bin3, chi3;
    find_parallel(gH3, 2048, K - chi1 - chi2, sm.u.p2.s, sm.u.p2.sc2, &bin3, &chi3);
    uint32_t t_u = (bin1 << 22) | (bin2 << 11) | bin3;
    uint32_t m_ties = K - (chi1 + chi2 + chi3);  // >= 1
    const uint32_t u_conf = 0xBE800000u;         // map_f(0.25f)
    bool tcut = (t_u >= u_conf);
    float lsum = 0.f;
    for (int r = gid; r < n; r += gstride) {
        uint32_t u = scores[r];
        bool sel = tcut ? (u > t_u) : (u >= u_conf);
        if (sel) {
            float4 b = *(const float4*)(pred + (size_t)r * ROWLEN);
            lsum += unmap_f(u) + b.x + b.y + b.z + b.w;
        }
        if (tcut && u == t_u) {
            uint32_t pos = atomicAdd(tieCnt, 1u);
            if (pos < TIECAP) tieBuf[pos] = (uint32_t)r;
        }
    }
    for (int off = 32; off; off >>= 1) lsum += __shfl_down(lsum, off);
    int wid = tid >> 6, lane = tid & 63;
    if (lane == 0) sm.u.p2.wsum[wid] = lsum;
    __syncthreads();
    if (tid == 0)
        atomicAdd(out, sm.u.p2.wsum[0] + sm.u.p2.wsum[1] + sm.u.p2.wsum[2] + sm.u.p2.wsum[3]);
    grid.sync();

    // ---- P5: block 0 resolves ties (m lowest-index rows at exactly t_u) ----
    if (blockIdx.x == 0 && tcut) {
        uint32_t cnt = *tieCnt;
        if (cnt > TIECAP) cnt = TIECAP;
        float tsum = 0.f;
        if (m_ties >= cnt) {
            for (uint32_t i = tid; i < cnt; i += 256) {
                uint32_t r = tieBuf[i];
                float4 b = *(const float4*)(pred + (size_t)r * ROWLEN);
                tsum += b.x + b.y + b.z + b.w;
            }
        } else {
            for (uint32_t i = tid; i < cnt; i += 256) {
                uint32_t ri = tieBuf[i];
                uint32_t rank = 0;
                for (uint32_t j = 0; j < cnt; ++j) rank += (tieBuf[j] < ri) ? 1u : 0u;
                if (rank < m_ties) {
                    float4 b = *(const float4*)(pred + (size_t)ri * ROWLEN);
                    tsum += b.x + b.y + b.z + b.w;
                }
            }
        }
        for (int off = 32; off; off >>= 1) tsum += __shfl_down(tsum, off);
        if (lane == 0) sm.u.p2.wsum[wid] = tsum;
        __syncthreads();
        if (tid == 0)
            atomicAdd(out, sm.u.p2.wsum[0] + sm.u.p2.wsum[1] + sm.u.p2.wsum[2] + sm.u.p2.wsum[3]
                           + (float)m_ties * unmap_f(t_u));
    }
}

// ======================= fallback multi-kernel path (round-3, known-good) =======================

__global__ __launch_bounds__(256) void k_score_hist(const float* __restrict__ pred,
                                                    uint32_t* __restrict__ scores,
                                                    uint32_t* __restrict__ gH1,
                                                    uint32_t* __restrict__ ticket, int n) {
    __shared__ float pm[F4PT];
    __shared__ uint32_t h[1024];
    __shared__ int s_tile;
    int tid = threadIdx.x;
    for (int i = tid; i < 1024; i += 256) h[i] = 0;
    uint32_t tid21 = (uint32_t)tid % 21u;
    const float4* pf4 = (const float4*)pred;
    size_t total_f4 = (size_t)n * F4PR;
    int ntiles = (n + RPB - 1) / RPB;
    for (;;) {
        __syncthreads();
        if (tid == 0) s_tile = (int)atomicAdd(ticket, 1u);
        __syncthreads();
        int tile = s_tile;
        if (tile >= ntiles) break;
        size_t gbase = (size_t)tile * F4PT;
        int row0 = tile * RPB;
        if (row0 + RPB <= n) {
#pragma unroll
            for (int it = 0; it < F4PR; ++it) {
                const uint32_t BP = (21u - (4u * (uint32_t)it) % 21u) % 21u;
                float4 v = pf4[gbase + it * 256 + tid];
                float m = fmaxf(fmaxf(v.x, v.y), fmaxf(v.z, v.w));
                pm[it * 256 + tid] = (tid21 == BP) ? -INFINITY : m;
            }
        } else {
#pragma unroll
            for (int it = 0; it < F4PR; ++it) {
                const uint32_t BP = (21u - (4u * (uint32_t)it) % 21u) % 21u;
                int l = it * 256 + tid;
                size_t g = gbase + l;
                float m = -INFINITY;
                if (g < total_f4 && tid21 != BP) {
                    float4 v = pf4[g];
                    m = fmaxf(fmaxf(v.x, v.y), fmaxf(v.z, v.w));
                }
                pm[l] = m;
            }
        }
        __syncthreads();
        int row = row0 + tid;
        if (row < n) {
            const float* q = pm + tid * F4PR;
            float m = q[1];
#pragma unroll
            for (int j = 2; j <= 20; ++j) m = fmaxf(m, q[j]);
            uint32_t u = map_f(m);
            scores[row] = u;
            atomicAdd(&h[u >> 22], 1u);
        }
    }
    __syncthreads();
    for (int i = tid; i < 1024; i += 256)
        if (h[i]) atomicAdd(&gH1[i], h[i]);
}

__global__ void k_sel1(const uint32_t* __restrict__ gH1, uint32_t* __restrict__ sres, uint32_t K) {
    __shared__ uint32_t s[256];
    __shared__ uint32_t sc2[2];
    uint32_t bin, above;
    find_parallel(gH1, 1024, K, s, sc2, &bin, &above);
    if (threadIdx.x == 0) { sres[0] = bin; sres[1] = above; }
}

__global__ void k_hist2(const uint32_t* __restrict__ scores, const uint32_t* __restrict__ sres,
                        uint32_t* __restrict__ gH2, int n) {
    __shared__ uint32_t h[2048];
    for (int i = threadIdx.x; i < 2048; i += blockDim.x) h[i] = 0;
    __syncthreads();
    uint32_t bin1 = sres[0];
    int stride = gridDim.x * blockDim.x;
    for (int r = blockIdx.x * blockDim.x + threadIdx.x; r < n; r += stride) {
        uint32_t u = scores[r];
        if ((u >> 22) == bin1) atomicAdd(&h[(u >> 11) & 0x7FFu], 1u);
    }
    __syncthreads();
    for (int i = threadIdx.x; i < 2048; i += blockDim.x)
        if (h[i]) atomicAdd(&gH2[i], h[i]);
}

__global__ void k_sel2(const uint32_t* __restrict__ gH2, uint32_t* __restrict__ sres, uint32_t K) {
    __shared__ uint32_t s[256];
    __shared__ uint32_t sc2[2];
    uint32_t chi1 = sres[1];
    uint32_t bin, above;
    find_parallel(gH2, 2048, K - chi1, s, sc2, &bin, &above);
    if (threadIdx.x == 0) { sres[2] = bin; sres[3] = above; }
}

__global__ void k_hist3(const uint32_t* __restrict__ scores, const uint32_t* __restrict__ sres,
                        uint32_t* __restrict__ gH3, int n) {
    __shared__ uint32_t h[2048];
    for (int i = threadIdx.x; i < 2048; i += blockDim.x) h[i] = 0;
    __syncthreads();
    uint32_t pref = (sres[0] << 11) | sres[2];
    int stride = gridDim.x * blockDim.x;
    for (int r = blockIdx.x * blockDim.x + threadIdx.x; r < n; r += stride) {
        uint32_t u = scores[r];
        if ((u >> 11) == pref) atomicAdd(&h[u & 0x7FFu], 1u);
    }
    __syncthreads();
    for (int i = threadIdx.x; i < 2048; i += blockDim.x)
        if (h[i]) atomicAdd(&gH3[i], h[i]);
}

__global__ void k_sel3(const uint32_t* __restrict__ gH3, uint32_t* __restrict__ sres, uint32_t K) {
    __shared__ uint32_t s[256];
    __shared__ uint32_t sc2[2];
    uint32_t chi1 = sres[1], chi2 = sres[3];
    uint32_t bin, above;
    find_parallel(gH3, 2048, K - chi1 - chi2, s, sc2, &bin, &above);
    if (threadIdx.x == 0) {
        uint32_t t_u = (sres[0] << 22) | (sres[2] << 11) | bin;
        uint32_t C_gt = chi1 + chi2 + above;
        sres[4] = bin;
        sres[5] = above;
        sres[6] = t_u;
        sres[7] = K - C_gt;
    }
}

__global__ void k_select(const float* __restrict__ pred, const uint32_t* __restrict__ scores,
                         const uint32_t* __restrict__ sres,
                         uint32_t* __restrict__ tieCnt, uint32_t* __restrict__ tieBuf,
                         float* __restrict__ out, int n) {
    __shared__ float wsum[4];
    uint32_t t_u = sres[6];
    const uint32_t u_conf = 0xBE800000u;
    bool tcut = (t_u >= u_conf);
    float lsum = 0.f;
    int stride = gridDim.x * blockDim.x;
    for (int r = blockIdx.x * blockDim.x + threadIdx.x; r < n; r += stride) {
        uint32_t u = scores[r];
        bool sel = tcut ? (u > t_u) : (u >= u_conf);
        if (sel) {
            float4 b = *(const float4*)(pred + (size_t)r * ROWLEN);
            lsum += unmap_f(u) + b.x + b.y + b.z + b.w;
        }
        if (tcut && u == t_u) {
            uint32_t pos = atomicAdd(tieCnt, 1u);
            if (pos < TIECAP) tieBuf[pos] = (uint32_t)r;
        }
    }
    for (int off = 32; off; off >>= 1) lsum += __shfl_down(lsum, off);
    int wid = threadIdx.x >> 6, lane = threadIdx.x & 63;
    if (lane == 0) wsum[wid] = lsum;
    __syncthreads();
    if (threadIdx.x == 0) atomicAdd(out, wsum[0] + wsum[1] + wsum[2] + wsum[3]);
}

__global__ void k_ties(const float* __restrict__ pred, const uint32_t* __restrict__ sres,
                       const uint32_t* __restrict__ tieCnt, const uint32_t* __restrict__ tieBuf,
                       float* __restrict__ out) {
    __shared__ float wsum[4];
    uint32_t t_u = sres[6];
    const uint32_t u_conf = 0xBE800000u;
    if (t_u < u_conf) return;
    uint32_t m = sres[7];
    uint32_t cnt = *tieCnt;
    if (cnt > TIECAP) cnt = TIECAP;
    float lsum = 0.f;
    if (m >= cnt) {
        for (uint32_t i = threadIdx.x; i < cnt; i += blockDim.x) {
            uint32_t r = tieBuf[i];
            float4 b = *(const float4*)(pred + (size_t)r * ROWLEN);
            lsum += b.x + b.y + b.z + b.w;
        }
    } else {
        for (uint32_t i = threadIdx.x; i < cnt; i += blockDim.x) {
            uint32_t ri = tieBuf[i];
            uint32_t rank = 0;
            for (uint32_t j = 0; j < cnt; ++j) rank += (tieBuf[j] < ri) ? 1u : 0u;
            if (rank < m) {
                float4 b = *(const float4*)(pred + (size_t)ri * ROWLEN);
                lsum += b.x + b.y + b.z + b.w;
            }
        }
    }
    for (int off = 32; off; off >>= 1) lsum += __shfl_down(lsum, off);
    int wid = threadIdx.x >> 6, lane = threadIdx.x & 63;
    if (lane == 0) wsum[wid] = lsum;
    __syncthreads();
    if (threadIdx.x == 0)
        atomicAdd(out, wsum[0] + wsum[1] + wsum[2] + wsum[3] + (float)m * unmap_f(t_u));
}

// ======================= launcher =======================

extern "C" void kernel_launch(void* const* d_in, const int* in_sizes, int n_in,
                              void* d_out, int out_size, void* d_ws, size_t ws_size,
                              hipStream_t stream) {
    const float* pred = (const float*)d_in[0];
    int n = in_sizes[0] / ROWLEN;
    double kd = ceil((double)n * 0.1);
    long kk = (long)kd;
    if (kk < 1) kk = 1;
    if (kk > n) kk = n;
    uint32_t K = (uint32_t)kk;

    uint32_t* ws32 = (uint32_t*)d_ws;
    uint32_t* scores = ws32;        // n words
    uint32_t* gH1 = ws32 + n;       // 1024
    uint32_t* gH2 = gH1 + 1024;     // 2048
    uint32_t* gH3 = gH2 + 2048;     // 2048
    uint32_t* sres = gH3 + 2048;    // 16
    uint32_t* tieCnt = sres + 16;   // 16 (1 used)
    uint32_t* ticket = tieCnt + 16; // 16 (1 used)
    uint32_t* tieBuf = ticket + 16; // TIECAP words
    float* out = (float*)d_out;

    // Cooperative grid sized by the runtime's own occupancy math.
    int dev = 0;
    (void)hipGetDevice(&dev);
    int nCU = 0;
    (void)hipDeviceGetAttribute(&nCU, hipDeviceAttributeMultiprocessorCount, dev);
    int blkPerCU = 0;
    hipError_t qe = hipOccupancyMaxActiveBlocksPerMultiprocessor(&blkPerCU, k_fused, 256, 0);

    bool coop_ok = false;
    if (qe == hipSuccess && nCU > 0 && blkPerCU > 0) {
        int grid = blkPerCU * nCU;
        if (grid > 1024) grid = 1024;
        if (grid >= 64) {
            void* args[] = {(void*)&pred, (void*)&scores, (void*)&gH1, (void*)&gH2, (void*)&gH3,
                            (void*)&tieCnt, (void*)&ticket, (void*)&tieBuf, (void*)&out,
                            (void*)&n, (void*)&K};
            hipError_t le = hipLaunchCooperativeKernel((void*)k_fused, dim3(grid), dim3(256),
                                                       args, 0, stream);
            if (le == hipSuccess) coop_ok = true;
            else (void)hipGetLastError();  // clear, fall through to fallback
        }
    }

    if (!coop_ok) {
        hipMemsetAsync(d_out, 0, sizeof(float), stream);
        hipMemsetAsync(gH1, 0, (1024 + 2048 + 2048 + 16 + 16 + 16) * sizeof(uint32_t), stream);
        k_score_hist<<<2048, 256, 0, stream>>>(pred, scores, gH1, ticket, n);
        k_sel1<<<1, 256, 0, stream>>>(gH1, sres, K);
        k_hist2<<<1024, 256, 0, stream>>>(scores, sres, gH2, n);
        k_sel2<<<1, 256, 0, stream>>>(gH2, sres, K);
        k_hist3<<<1024, 256, 0, stream>>>(scores, sres, gH3, n);
        k_sel3<<<1, 256, 0, stream>>>(gH3, sres, K);
        k_select<<<2048, 256, 0, stream>>>(pred, scores, sres, tieCnt, tieBuf, out, n);
        k_ties<<<1, 256, 0, stream>>>(pred, sres, tieCnt, tieBuf, out);
    }
}

// Round 6
// 201.305 us; speedup vs baseline: 2.2306x; 2.2306x over previous
//
#include <hip/hip_runtime.h>
#include <stdint.h>
#include <math.h>

#define ROWLEN 84
#define F4PR 21            // float4s per row (84 floats)
#define RPB 256            // rows per tile
#define F4PT (RPB * F4PR)  // 5376 float4s per tile
#define TIECAP 16384u

__device__ __forceinline__ uint32_t map_f(float f) {
    uint32_t u = __float_as_uint(f);
    return (u & 0x80000000u) ? ~u : (u | 0x80000000u);
}
__device__ __forceinline__ float unmap_f(uint32_t u) {
    uint32_t b = (u & 0x80000000u) ? (u & 0x7FFFFFFFu) : ~u;
    return __uint_as_float(b);
}

// Parallel bin find: bin b with suffix_count(b+1..) < target <= suffix_count(b..).
// All 256 threads participate; returns identical (bin, count-strictly-above) to all.
__device__ void find_parallel(const uint32_t* __restrict__ hist, int nbins, uint32_t target,
                              uint32_t* s, uint32_t* sc2, uint32_t* outBin, uint32_t* outAbove) {
    int tid = threadIdx.x;
    int chunks = nbins / 256;
    int base = tid * chunks;
    uint32_t part = 0;
    for (int i = 0; i < chunks; ++i) part += hist[base + i];
    s[tid] = part;
    __syncthreads();
    for (int off = 1; off < 256; off <<= 1) {  // suffix sums
        uint32_t v = (tid + off < 256) ? s[tid + off] : 0u;
        __syncthreads();
        s[tid] += v;
        __syncthreads();
    }
    uint32_t above_next = (tid < 255) ? s[tid + 1] : 0u;
    bool mine = (s[tid] >= target) && (above_next < target);  // exactly one thread
    if (mine) { sc2[0] = (uint32_t)tid; sc2[1] = above_next; }
    __syncthreads();
    uint32_t c = sc2[0], above = sc2[1];
    if (tid == 0) {  // <= chunks serial reads (L2-broadcast across blocks)
        uint32_t acc = above;
        int b = (int)c * chunks + chunks - 1;
        for (;; --b) {
            uint32_t hb = hist[b];
            if (acc + hb >= target) break;
            acc += hb;
        }
        sc2[0] = (uint32_t)b;
        sc2[1] = acc;
    }
    __syncthreads();
    *outBin = sc2[0];
    *outAbove = sc2[1];
}

// Pass 1: scores + level-1 histogram (top 10 bits). Static 256-row tiles staged via LDS.
// Phase A: 21 coalesced 256-wide float4 loads -> per-float4 max -> pm[] (box lanes masked).
// Phase B: thread t reduces pm[21t+1 .. 21t+20] (2 lanes/bank = free), key + 1024-bin LDS hist.
// Block 0 also zeroes *out (safe: out untouched until k_selectf, 4 dispatches later).
__global__ __launch_bounds__(256) void k_score_hist(const float* __restrict__ pred,
                                                    uint32_t* __restrict__ scores,
                                                    uint32_t* __restrict__ gH1,
                                                    float* __restrict__ out, int n) {
    __shared__ float pm[F4PT];
    __shared__ uint32_t h[1024];
    int tid = threadIdx.x;
    if (blockIdx.x == 0 && tid == 0) *out = 0.f;
    for (int i = tid; i < 1024; i += 256) h[i] = 0;
    uint32_t tid21 = (uint32_t)tid % 21u;
    const float4* pf4 = (const float4*)pred;
    size_t total_f4 = (size_t)n * F4PR;
    int ntiles = (n + RPB - 1) / RPB;
    for (int tile = blockIdx.x; tile < ntiles; tile += gridDim.x) {
        __syncthreads();  // pm reuse guard (also covers h init on first tile)
        size_t gbase = (size_t)tile * F4PT;
        int row0 = tile * RPB;
        if (row0 + RPB <= n) {
#pragma unroll
            for (int it = 0; it < F4PR; ++it) {
                const uint32_t BP = (21u - (4u * (uint32_t)it) % 21u) % 21u;  // box lane
                float4 v = pf4[gbase + it * 256 + tid];
                float m = fmaxf(fmaxf(v.x, v.y), fmaxf(v.z, v.w));
                pm[it * 256 + tid] = (tid21 == BP) ? -INFINITY : m;
            }
        } else {
#pragma unroll
            for (int it = 0; it < F4PR; ++it) {
                const uint32_t BP = (21u - (4u * (uint32_t)it) % 21u) % 21u;
                int l = it * 256 + tid;
                size_t g = gbase + l;
                float m = -INFINITY;
                if (g < total_f4 && tid21 != BP) {
                    float4 v = pf4[g];
                    m = fmaxf(fmaxf(v.x, v.y), fmaxf(v.z, v.w));
                }
                pm[l] = m;
            }
        }
        __syncthreads();
        int row = row0 + tid;
        if (row < n) {
            const float* q = pm + tid * F4PR;
            float m = q[1];
#pragma unroll
            for (int j = 2; j <= 20; ++j) m = fmaxf(m, q[j]);
            uint32_t u = map_f(m);
            scores[row] = u;
            atomicAdd(&h[u >> 22], 1u);
        }
    }
    __syncthreads();
    for (int i = tid; i < 1024; i += 256)
        if (h[i]) atomicAdd(&gH1[i], h[i]);
}

// Pass 2: every block computes find1(gH1) itself (no dedicated sel kernel);
// block 0 persists bin1/chi1 to sres. Level-2 histogram of bits [21:11].
__global__ void k_hist2f(const uint32_t* __restrict__ scores, const uint32_t* __restrict__ gH1,
                         uint32_t* __restrict__ gH2, uint32_t* __restrict__ sres,
                         int n, uint32_t K) {
    __shared__ uint32_t h[2048];
    __shared__ uint32_t s[256];
    __shared__ uint32_t sc2[2];
    for (int i = threadIdx.x; i < 2048; i += 256) h[i] = 0;
    uint32_t bin1, chi1;
    find_parallel(gH1, 1024, K, s, sc2, &bin1, &chi1);
    if (blockIdx.x == 0 && threadIdx.x == 0) { sres[0] = bin1; sres[1] = chi1; }
    int stride = gridDim.x * 256;
    for (int r = blockIdx.x * 256 + threadIdx.x; r < n; r += stride) {
        uint32_t u = scores[r];
        if ((u >> 22) == bin1) atomicAdd(&h[(u >> 11) & 0x7FFu], 1u);
    }
    __syncthreads();
    for (int i = threadIdx.x; i < 2048; i += 256)
        if (h[i]) atomicAdd(&gH2[i], h[i]);
}

// Pass 3: reads bin1/chi1 from sres; computes find2(gH2); block 0 persists bin2/chi2.
// Level-3 histogram of bits [10:0].
__global__ void k_hist3f(const uint32_t* __restrict__ scores, const uint32_t* __restrict__ gH2,
                         uint32_t* __restrict__ gH3, uint32_t* __restrict__ sres,
                         int n, uint32_t K) {
    __shared__ uint32_t h[2048];
    __shared__ uint32_t s[256];
    __shared__ uint32_t sc2[2];
    for (int i = threadIdx.x; i < 2048; i += 256) h[i] = 0;
    uint32_t bin1 = sres[0], chi1 = sres[1];
    uint32_t bin2, chi2;
    find_parallel(gH2, 2048, K - chi1, s, sc2, &bin2, &chi2);
    if (blockIdx.x == 0 && threadIdx.x == 0) { sres[2] = bin2; sres[3] = chi2; }
    uint32_t pref = (bin1 << 11) | bin2;
    int stride = gridDim.x * 256;
    for (int r = blockIdx.x * 256 + threadIdx.x; r < n; r += stride) {
        uint32_t u = scores[r];
        if ((u >> 11) == pref) atomicAdd(&h[u & 0x7FFu], 1u);
    }
    __syncthreads();
    for (int i = threadIdx.x; i < 2048; i += 256)
        if (h[i]) atomicAdd(&gH3[i], h[i]);
}

// Pass 4: computes find3(gH3) -> threshold; block 0 persists t_u and tie count m.
// Selection sum: strictly-greater rows contribute score + boxes; ties recorded.
__global__ void k_selectf(const float* __restrict__ pred, const uint32_t* __restrict__ scores,
                          const uint32_t* __restrict__ gH3, uint32_t* __restrict__ sres,
                          uint32_t* __restrict__ tieCnt, uint32_t* __restrict__ tieBuf,
                          float* __restrict__ out, int n, uint32_t K) {
    __shared__ uint32_t s[256];
    __shared__ uint32_t sc2[2];
    __shared__ float wsum[4];
    uint32_t bin1 = sres[0], chi1 = sres[1];
    uint32_t bin2 = sres[2], chi2 = sres[3];
    uint32_t bin3, chi3;
    find_parallel(gH3, 2048, K - chi1 - chi2, s, sc2, &bin3, &chi3);
    uint32_t t_u = (bin1 << 22) | (bin2 << 11) | bin3;
    uint32_t m_ties = K - (chi1 + chi2 + chi3);  // >= 1
    if (blockIdx.x == 0 && threadIdx.x == 0) { sres[6] = t_u; sres[7] = m_ties; }
    const uint32_t u_conf = 0xBE800000u;  // map_f(0.25f)
    bool tcut = (t_u >= u_conf);
    float lsum = 0.f;
    int stride = gridDim.x * 256;
    for (int r = blockIdx.x * 256 + threadIdx.x; r < n; r += stride) {
        uint32_t u = scores[r];
        bool sel = tcut ? (u > t_u) : (u >= u_conf);
        if (sel) {
            float4 b = *(const float4*)(pred + (size_t)r * ROWLEN);
            lsum += unmap_f(u) + b.x + b.y + b.z + b.w;
        }
        if (tcut && u == t_u) {
            uint32_t pos = atomicAdd(tieCnt, 1u);
            if (pos < TIECAP) tieBuf[pos] = (uint32_t)r;
        }
    }
    for (int off = 32; off; off >>= 1) lsum += __shfl_down(lsum, off);
    int wid = threadIdx.x >> 6, lane = threadIdx.x & 63;
    if (lane == 0) wsum[wid] = lsum;
    __syncthreads();
    if (threadIdx.x == 0) atomicAdd(out, wsum[0] + wsum[1] + wsum[2] + wsum[3]);
}

// Pass 5: include the m lowest-index tied rows (boxes + m * t).
__global__ void k_ties(const float* __restrict__ pred, const uint32_t* __restrict__ sres,
                       const uint32_t* __restrict__ tieCnt, const uint32_t* __restrict__ tieBuf,
                       float* __restrict__ out) {
    __shared__ float wsum[4];
    uint32_t t_u = sres[6];
    const uint32_t u_conf = 0xBE800000u;
    if (t_u < u_conf) return;  // selection was score >= CONF; fully handled in k_selectf
    uint32_t m = sres[7];
    uint32_t cnt = *tieCnt;
    if (cnt > TIECAP) cnt = TIECAP;
    float lsum = 0.f;
    if (m >= cnt) {
        for (uint32_t i = threadIdx.x; i < cnt; i += blockDim.x) {
            uint32_t r = tieBuf[i];
            float4 b = *(const float4*)(pred + (size_t)r * ROWLEN);
            lsum += b.x + b.y + b.z + b.w;
        }
    } else {
        for (uint32_t i = threadIdx.x; i < cnt; i += blockDim.x) {
            uint32_t ri = tieBuf[i];
            uint32_t rank = 0;
            for (uint32_t j = 0; j < cnt; ++j) rank += (tieBuf[j] < ri) ? 1u : 0u;
            if (rank < m) {
                float4 b = *(const float4*)(pred + (size_t)ri * ROWLEN);
                lsum += b.x + b.y + b.z + b.w;
            }
        }
    }
    for (int off = 32; off; off >>= 1) lsum += __shfl_down(lsum, off);
    int wid = threadIdx.x >> 6, lane = threadIdx.x & 63;
    if (lane == 0) wsum[wid] = lsum;
    __syncthreads();
    if (threadIdx.x == 0)
        atomicAdd(out, wsum[0] + wsum[1] + wsum[2] + wsum[3] + (float)m * unmap_f(t_u));
}

extern "C" void kernel_launch(void* const* d_in, const int* in_sizes, int n_in,
                              void* d_out, int out_size, void* d_ws, size_t ws_size,
                              hipStream_t stream) {
    const float* pred = (const float*)d_in[0];
    int n = in_sizes[0] / ROWLEN;
    double kd = ceil((double)n * 0.1);
    long kk = (long)kd;
    if (kk < 1) kk = 1;
    if (kk > n) kk = n;
    uint32_t K = (uint32_t)kk;

    uint32_t* ws32 = (uint32_t*)d_ws;
    uint32_t* scores = ws32;        // n words
    uint32_t* gH1 = ws32 + n;       // 1024
    uint32_t* gH2 = gH1 + 1024;     // 2048
    uint32_t* gH3 = gH2 + 2048;     // 2048
    uint32_t* tieCnt = gH3 + 2048;  // 16 (1 used) -- contiguous with hists for one memset
    uint32_t* sres = tieCnt + 16;   // 16
    uint32_t* tieBuf = sres + 16;   // TIECAP words
    float* out = (float*)d_out;

    // One memset covers gH1 | gH2 | gH3 | tieCnt (contiguous).
    hipMemsetAsync(gH1, 0, (1024 + 2048 + 2048 + 16) * sizeof(uint32_t), stream);

    k_score_hist<<<2048, 256, 0, stream>>>(pred, scores, gH1, out, n);
    k_hist2f<<<1024, 256, 0, stream>>>(scores, gH1, gH2, sres, n, K);
    k_hist3f<<<1024, 256, 0, stream>>>(scores, gH2, gH3, sres, n, K);
    k_selectf<<<2048, 256, 0, stream>>>(pred, scores, gH3, sres, tieCnt, tieBuf, out, n, K);
    k_ties<<<1, 256, 0, stream>>>(pred, sres, tieCnt, tieBuf, out);
}